// Round 1
// baseline (2182.792 us; speedup 1.0000x reference)
//
#include <hip/hip_runtime.h>
#include <hip/hip_bf16.h>
#include <math.h>

#define B_ 8
#define N_ 2048
#define KNN 20
#define CH 64

typedef unsigned int u32;

__device__ __forceinline__ float lrelu(float z) { return z >= 0.0f ? z : 0.2f * z; }

__device__ __forceinline__ u32 enc_f32(float f) {
  u32 u = __float_as_uint(f);
  return (u & 0x80000000u) ? ~u : (u | 0x80000000u);
}
__device__ __forceinline__ float dec_f32(u32 u) {
  u32 bits = (u & 0x80000000u) ? (u ^ 0x80000000u) : ~u;
  return __uint_as_float(bits);
}

// ---------------- prep: transpose W2/W4/W6 into ws, zero gmax keys ----------------
__global__ __launch_bounds__(256) void prep_kernel(
    const float* __restrict__ W2, const float* __restrict__ W4, const float* __restrict__ W6,
    float* __restrict__ w2tg, float* __restrict__ w4tg, float* __restrict__ w6t,
    u32* __restrict__ gkeys) {
  int i = blockIdx.x * 256 + threadIdx.x;
  if (i < 192 * 1024) {          // w6t[d*1024+c] = W6[c*192+d]
    int cc = i / 192, d = i % 192;
    w6t[d * 1024 + cc] = W6[i];
  }
  if (i < 4096) {                // w2tg[cc*64+c] = W2[c*64+cc]; same for W4
    int c_ = i >> 6, cc = i & 63;
    w2tg[cc * 64 + c_] = W2[i];
    w4tg[cc * 64 + c_] = W4[i];
  }
  if (i < 8192) gkeys[i] = 0u;
}

// ---------------- KNN: top-20 smallest squared distance (fp64), ties -> lower index ----------------
// grid (N/64, B), block 256 = 64 queries x 4 j-slices
__global__ __launch_bounds__(256) void knn_kernel(const float* __restrict__ p, int ld, int off,
                                                  int* __restrict__ idxout) {
  __shared__ __align__(16) char smem[61440];
  float* sx = (float*)smem;             // [2048] (phase 1)
  float* sy = sx + N_;
  float* sz = sy + N_;
  double* md = (double*)smem;           // [256][20] (phase 2, aliases coords)
  int* mi = (int*)(smem + 40960);       // [256][20]

  const int b = blockIdx.y;
  const float* pb = p + (size_t)b * N_ * ld + off;
  for (int j = threadIdx.x; j < N_; j += 256) {
    sx[j] = pb[(size_t)j * ld + 0];
    sy[j] = pb[(size_t)j * ld + 1];
    sz[j] = pb[(size_t)j * ld + 2];
  }
  __syncthreads();

  const int t = threadIdx.x & 3;
  const int qloc = threadIdx.x >> 2;
  const int q = blockIdx.x * 64 + qloc;
  const double qx = (double)sx[q], qy = (double)sy[q], qz = (double)sz[q];

  double bd[KNN]; int bi[KNN];
#pragma unroll
  for (int u = 0; u < KNN; ++u) { bd[u] = 1e300; bi[u] = 0; }

  const int jbeg = t * (N_ / 4);
  for (int j = jbeg; j < jbeg + N_ / 4; ++j) {
    double dx = qx - (double)sx[j];
    double dy = qy - (double)sy[j];
    double dz = qz - (double)sz[j];
    double d = dx * dx + dy * dy + dz * dz;
    if (d < bd[KNN - 1]) {               // strict <: equal dist keeps earlier index (top_k tie rule)
      bd[KNN - 1] = d; bi[KNN - 1] = j;
#pragma unroll
      for (int u = KNN - 1; u > 0; --u) {
        if (bd[u] < bd[u - 1]) {
          double td = bd[u]; bd[u] = bd[u - 1]; bd[u - 1] = td;
          int ti = bi[u]; bi[u] = bi[u - 1]; bi[u - 1] = ti;
        }
      }
    }
  }
  __syncthreads();                       // coords dead; reuse LDS for merge lists
  {
    double* mdr = md + (size_t)threadIdx.x * KNN;
    int* mir = mi + (size_t)threadIdx.x * KNN;
#pragma unroll
    for (int u = 0; u < KNN; ++u) { mdr[u] = bd[u]; mir[u] = bi[u]; }
  }
  __syncthreads();

  if (threadIdx.x < 64) {                // 4-way merge of sorted lists, lexicographic (d, idx)
    const int r0 = threadIdx.x * 4;
    const double* l0 = md + (size_t)r0 * KNN;
    const double* l1 = l0 + KNN;
    const double* l2 = l1 + KNN;
    const double* l3 = l2 + KNN;
    const int* m0 = mi + (size_t)r0 * KNN;
    const int* m1 = m0 + KNN;
    const int* m2 = m1 + KNN;
    const int* m3 = m2 + KNN;
    int i0 = 0, i1 = 0, i2 = 0, i3 = 0;
    int* outp = idxout + ((size_t)b * N_ + blockIdx.x * 64 + threadIdx.x) * KNN;
    for (int u = 0; u < KNN; ++u) {
      double d0 = l0[i0], d1 = l1[i1], d2 = l2[i2], d3 = l3[i3];
      int a0 = m0[i0], a1 = m1[i1], a2 = m2[i2], a3 = m3[i3];
      bool s01 = (d0 < d1) || (d0 == d1 && a0 < a1);
      double da = s01 ? d0 : d1; int ja = s01 ? a0 : a1; int wa = s01 ? 0 : 1;
      bool s23 = (d2 < d3) || (d2 == d3 && a2 < a3);
      double db = s23 ? d2 : d3; int jb = s23 ? a2 : a3; int wb = s23 ? 2 : 3;
      bool sab = (da < db) || (da == db && ja < jb);
      int wm = sab ? wa : wb;
      outp[u] = sab ? ja : jb;
      i0 += (wm == 0); i1 += (wm == 1); i2 += (wm == 2); i3 += (wm == 3);
    }
  }
}

// ---------------- stage1: edge(3) -> 64 -> 64 -> max_k ----------------
// grid (N/4, B), block 256 = 4 points x 64 channels
__global__ __launch_bounds__(256) void stage1_kernel(
    const float* __restrict__ x, const int* __restrict__ idx,
    const float* __restrict__ W1, const float* __restrict__ w2tg,
    const float* __restrict__ g0, const float* __restrict__ b0,
    const float* __restrict__ m0, const float* __restrict__ v0,
    const float* __restrict__ g1, const float* __restrict__ b1,
    const float* __restrict__ m1, const float* __restrict__ v1,
    float* __restrict__ x1out) {
  __shared__ float w1t[6][CH];
  __shared__ float nbs[4][KNN][3];
  __shared__ float ctrs[4][3];
  __shared__ int sidx[4][KNN];
  const int b = blockIdx.y;
  const int n0 = blockIdx.x * 4;
  const int p = threadIdx.x >> 6, c = threadIdx.x & 63;

  for (int i = threadIdx.x; i < 6 * CH; i += 256) { int d = i >> 6, cc = i & 63; w1t[d][cc] = W1[cc * 6 + d]; }
  for (int i = threadIdx.x; i < 4 * KNN; i += 256)
    sidx[i / KNN][i % KNN] = idx[((size_t)b * N_ + n0 + i / KNN) * KNN + i % KNN];
  __syncthreads();
  for (int i = threadIdx.x; i < 4 * KNN * 3; i += 256) {
    int pp = i / (KNN * 3), r = i % (KNN * 3), k = r / 3, d = r % 3;
    nbs[pp][k][d] = x[((size_t)b * N_ + sidx[pp][k]) * 3 + d];
  }
  if (threadIdx.x < 12) {
    int pp = threadIdx.x / 3, d = threadIdx.x % 3;
    ctrs[pp][d] = x[((size_t)b * N_ + n0 + pp) * 3 + d];
  }
  __syncthreads();

  float sc0, sh0, sc1, sh1;
  {
    double rs = 1.0 / sqrt((double)v0[c] + 1e-5);
    sc0 = (float)((double)g0[c] * rs); sh0 = b0[c] - m0[c] * sc0;
    rs = 1.0 / sqrt((double)v1[c] + 1e-5);
    sc1 = (float)((double)g1[c] * rs); sh1 = b1[c] - m1[c] * sc1;
  }

  const float cx = ctrs[p][0], cy = ctrs[p][1], cz = ctrs[p][2];
  const float wa0 = w1t[0][c], wa1 = w1t[1][c], wa2 = w1t[2][c];
  const float wb0 = w1t[3][c], wb1 = w1t[4][c], wb2 = w1t[5][c];
  const float cbase = cx * wb0 + cy * wb1 + cz * wb2;

  float h1r[KNN];
#pragma unroll
  for (int k = 0; k < KNN; ++k) {
    float a = (nbs[p][k][0] - cx) * wa0 + (nbs[p][k][1] - cy) * wa1 + (nbs[p][k][2] - cz) * wa2 + cbase;
    h1r[k] = lrelu(a * sc0 + sh0);
  }

  float acc2[KNN];
#pragma unroll
  for (int k = 0; k < KNN; ++k) acc2[k] = 0.f;
  for (int cc = 0; cc < CH; ++cc) {
    float w = w2tg[cc * CH + c];
#pragma unroll
    for (int k = 0; k < KNN; ++k) {
      float hv = __int_as_float(__builtin_amdgcn_readlane(__float_as_int(h1r[k]), cc));
      acc2[k] += hv * w;
    }
  }
  float mx = -INFINITY;
#pragma unroll
  for (int k = 0; k < KNN; ++k) mx = fmaxf(mx, lrelu(acc2[k] * sc1 + sh1));
  x1out[((size_t)b * N_ + n0 + p) * CH + c] = mx;
}

// ---------------- stage2: edge(64) -> 64 -> 64 -> max_k ----------------
__global__ __launch_bounds__(256) void stage2_kernel(
    const float* __restrict__ xin, const int* __restrict__ idx,
    const float* __restrict__ W3, const float* __restrict__ w4tg,
    const float* __restrict__ g0, const float* __restrict__ b0,
    const float* __restrict__ m0, const float* __restrict__ v0,
    const float* __restrict__ g1, const float* __restrict__ b1,
    const float* __restrict__ m1, const float* __restrict__ v1,
    float* __restrict__ xout) {
  __shared__ float w3t[128][CH];      // 32KB
  __shared__ float nbs[4][KNN][CH];   // 20KB
  __shared__ float ctrs[4][CH];       // 1KB
  __shared__ int sidx[4][KNN];
  const int b = blockIdx.y, n0 = blockIdx.x * 4;
  const int p = threadIdx.x >> 6, c = threadIdx.x & 63;

  for (int i = threadIdx.x; i < 128 * CH; i += 256) { int cc = i >> 7, d = i & 127; w3t[d][cc] = W3[i]; }
  for (int i = threadIdx.x; i < 4 * KNN; i += 256)
    sidx[i / KNN][i % KNN] = idx[((size_t)b * N_ + n0 + i / KNN) * KNN + i % KNN];
  __syncthreads();
  for (int i = threadIdx.x; i < 4 * KNN * 16; i += 256) {
    int pp = i / (KNN * 16), r = i % (KNN * 16), k = r >> 4, d4 = (r & 15) * 4;
    const float4 v = *(const float4*)&xin[((size_t)b * N_ + sidx[pp][k]) * CH + d4];
    *(float4*)&nbs[pp][k][d4] = v;
  }
  for (int i = threadIdx.x; i < 4 * 16; i += 256) {
    int pp = i / 16, d4 = (i % 16) * 4;
    *(float4*)&ctrs[pp][d4] = *(const float4*)&xin[((size_t)b * N_ + n0 + pp) * CH + d4];
  }
  __syncthreads();

  float sc0, sh0, sc1, sh1;
  {
    double rs = 1.0 / sqrt((double)v0[c] + 1e-5);
    sc0 = (float)((double)g0[c] * rs); sh0 = b0[c] - m0[c] * sc0;
    rs = 1.0 / sqrt((double)v1[c] + 1e-5);
    sc1 = (float)((double)g1[c] * rs); sh1 = b1[c] - m1[c] * sc1;
  }

  float acc[KNN];
#pragma unroll
  for (int k = 0; k < KNN; ++k) acc[k] = 0.f;
  float base = 0.f;
  for (int d = 0; d < CH; d += 4) {
    float a0 = w3t[d + 0][c], a1 = w3t[d + 1][c], a2 = w3t[d + 2][c], a3 = w3t[d + 3][c];
    float q0 = w3t[64 + d + 0][c], q1 = w3t[64 + d + 1][c], q2 = w3t[64 + d + 2][c], q3 = w3t[64 + d + 3][c];
    const float4 ct = *(const float4*)&ctrs[p][d];
    base += ct.x * (q0 - a0) + ct.y * (q1 - a1) + ct.z * (q2 - a2) + ct.w * (q3 - a3);
#pragma unroll
    for (int k = 0; k < KNN; ++k) {
      const float4 nb = *(const float4*)&nbs[p][k][d];
      acc[k] += nb.x * a0 + nb.y * a1 + nb.z * a2 + nb.w * a3;
    }
  }
  float h1r[KNN];
#pragma unroll
  for (int k = 0; k < KNN; ++k) h1r[k] = lrelu((acc[k] + base) * sc0 + sh0);

  float acc2[KNN];
#pragma unroll
  for (int k = 0; k < KNN; ++k) acc2[k] = 0.f;
  for (int cc = 0; cc < CH; ++cc) {
    float w = w4tg[cc * CH + c];
#pragma unroll
    for (int k = 0; k < KNN; ++k) {
      float hv = __int_as_float(__builtin_amdgcn_readlane(__float_as_int(h1r[k]), cc));
      acc2[k] += hv * w;
    }
  }
  float mx = -INFINITY;
#pragma unroll
  for (int k = 0; k < KNN; ++k) mx = fmaxf(mx, lrelu(acc2[k] * sc1 + sh1));
  xout[((size_t)b * N_ + n0 + p) * CH + c] = mx;
}

// ---------------- stage3: edge(64) -> 64 -> max_k ----------------
__global__ __launch_bounds__(256) void stage3_kernel(
    const float* __restrict__ xin, const int* __restrict__ idx,
    const float* __restrict__ W5,
    const float* __restrict__ g0, const float* __restrict__ b0,
    const float* __restrict__ m0, const float* __restrict__ v0,
    float* __restrict__ xout) {
  __shared__ float w5t[128][CH];
  __shared__ float nbs[4][KNN][CH];
  __shared__ float ctrs[4][CH];
  __shared__ int sidx[4][KNN];
  const int b = blockIdx.y, n0 = blockIdx.x * 4;
  const int p = threadIdx.x >> 6, c = threadIdx.x & 63;

  for (int i = threadIdx.x; i < 128 * CH; i += 256) { int cc = i >> 7, d = i & 127; w5t[d][cc] = W5[i]; }
  for (int i = threadIdx.x; i < 4 * KNN; i += 256)
    sidx[i / KNN][i % KNN] = idx[((size_t)b * N_ + n0 + i / KNN) * KNN + i % KNN];
  __syncthreads();
  for (int i = threadIdx.x; i < 4 * KNN * 16; i += 256) {
    int pp = i / (KNN * 16), r = i % (KNN * 16), k = r >> 4, d4 = (r & 15) * 4;
    const float4 v = *(const float4*)&xin[((size_t)b * N_ + sidx[pp][k]) * CH + d4];
    *(float4*)&nbs[pp][k][d4] = v;
  }
  for (int i = threadIdx.x; i < 4 * 16; i += 256) {
    int pp = i / 16, d4 = (i % 16) * 4;
    *(float4*)&ctrs[pp][d4] = *(const float4*)&xin[((size_t)b * N_ + n0 + pp) * CH + d4];
  }
  __syncthreads();

  float sc0, sh0;
  {
    double rs = 1.0 / sqrt((double)v0[c] + 1e-5);
    sc0 = (float)((double)g0[c] * rs); sh0 = b0[c] - m0[c] * sc0;
  }

  float acc[KNN];
#pragma unroll
  for (int k = 0; k < KNN; ++k) acc[k] = 0.f;
  float base = 0.f;
  for (int d = 0; d < CH; d += 4) {
    float a0 = w5t[d + 0][c], a1 = w5t[d + 1][c], a2 = w5t[d + 2][c], a3 = w5t[d + 3][c];
    float q0 = w5t[64 + d + 0][c], q1 = w5t[64 + d + 1][c], q2 = w5t[64 + d + 2][c], q3 = w5t[64 + d + 3][c];
    const float4 ct = *(const float4*)&ctrs[p][d];
    base += ct.x * (q0 - a0) + ct.y * (q1 - a1) + ct.z * (q2 - a2) + ct.w * (q3 - a3);
#pragma unroll
    for (int k = 0; k < KNN; ++k) {
      const float4 nb = *(const float4*)&nbs[p][k][d];
      acc[k] += nb.x * a0 + nb.y * a1 + nb.z * a2 + nb.w * a3;
    }
  }
  float mx = -INFINITY;
#pragma unroll
  for (int k = 0; k < KNN; ++k) mx = fmaxf(mx, lrelu((acc[k] + base) * sc0 + sh0));
  xout[((size_t)b * N_ + n0 + p) * CH + c] = mx;
}

// ---------------- stage6: x4(192) -> 1024, BN+LReLU, block-local max + atomic ----------------
// grid (N/16, B), block 256; thread owns 4 channels, 16 points per block
__global__ __launch_bounds__(256) void stage6_kernel(
    const float* __restrict__ x1, const float* __restrict__ x2, const float* __restrict__ x3,
    const float* __restrict__ w6t,
    const float* __restrict__ g6, const float* __restrict__ b6,
    const float* __restrict__ m6, const float* __restrict__ v6,
    u32* __restrict__ gkeys) {
  __shared__ float xsT[192][16];
  const int b = blockIdx.y;
  const int n0 = blockIdx.x * 16;
  for (int i = threadIdx.x; i < 16 * 192; i += 256) {
    int d = i >> 4, pp = i & 15;
    float v;
    if (d < 64)       v = x1[((size_t)b * N_ + n0 + pp) * CH + d];
    else if (d < 128) v = x2[((size_t)b * N_ + n0 + pp) * CH + (d - 64)];
    else              v = x3[((size_t)b * N_ + n0 + pp) * CH + (d - 128)];
    xsT[d][pp] = v;
  }
  __syncthreads();

  const int c0 = threadIdx.x << 2;
  float4 acc[16];
#pragma unroll
  for (int pp = 0; pp < 16; ++pp) acc[pp] = make_float4(0.f, 0.f, 0.f, 0.f);

  for (int d = 0; d < 192; ++d) {
    const float4 w = *(const float4*)&w6t[(size_t)d * 1024 + c0];
#pragma unroll
    for (int q = 0; q < 4; ++q) {
      const float4 xq = *(const float4*)&xsT[d][q * 4];
#define ACC4(J, XV) { float4& A = acc[q * 4 + (J)]; A.x += (XV) * w.x; A.y += (XV) * w.y; A.z += (XV) * w.z; A.w += (XV) * w.w; }
      ACC4(0, xq.x) ACC4(1, xq.y) ACC4(2, xq.z) ACC4(3, xq.w)
#undef ACC4
    }
  }

  const float4 gg = *(const float4*)&g6[c0];
  const float4 bb = *(const float4*)&b6[c0];
  const float4 mm = *(const float4*)&m6[c0];
  const float4 vv = *(const float4*)&v6[c0];
  float4 s, h;
  s.x = (float)((double)gg.x / sqrt((double)vv.x + 1e-5)); h.x = bb.x - mm.x * s.x;
  s.y = (float)((double)gg.y / sqrt((double)vv.y + 1e-5)); h.y = bb.y - mm.y * s.y;
  s.z = (float)((double)gg.z / sqrt((double)vv.z + 1e-5)); h.z = bb.z - mm.z * s.z;
  s.w = (float)((double)gg.w / sqrt((double)vv.w + 1e-5)); h.w = bb.w - mm.w * s.w;

  float4 mx = make_float4(-INFINITY, -INFINITY, -INFINITY, -INFINITY);
#pragma unroll
  for (int pp = 0; pp < 16; ++pp) {
    mx.x = fmaxf(mx.x, lrelu(acc[pp].x * s.x + h.x));
    mx.y = fmaxf(mx.y, lrelu(acc[pp].y * s.y + h.y));
    mx.z = fmaxf(mx.z, lrelu(acc[pp].z * s.z + h.z));
    mx.w = fmaxf(mx.w, lrelu(acc[pp].w * s.w + h.w));
  }
  u32* gk = gkeys + (size_t)b * 1024 + c0;
  atomicMax(&gk[0], enc_f32(mx.x));
  atomicMax(&gk[1], enc_f32(mx.y));
  atomicMax(&gk[2], enc_f32(mx.z));
  atomicMax(&gk[3], enc_f32(mx.w));
}

__global__ __launch_bounds__(256) void feat_kernel(const u32* __restrict__ gkeys, float* __restrict__ out) {
  int i = blockIdx.x * 256 + threadIdx.x;
  if (i < 8192) out[i] = dec_f32(gkeys[i]);
}

// out1[b][c][n] = x4[b][n][c]; grid (N/256, 192, B)
__global__ __launch_bounds__(256) void xpose_kernel(
    const float* __restrict__ x1, const float* __restrict__ x2, const float* __restrict__ x3,
    float* __restrict__ out) {
  int n = blockIdx.x * 256 + threadIdx.x;
  int cc = blockIdx.y, b = blockIdx.z;
  float v;
  if (cc < 64)       v = x1[((size_t)b * N_ + n) * CH + cc];
  else if (cc < 128) v = x2[((size_t)b * N_ + n) * CH + (cc - 64)];
  else               v = x3[((size_t)b * N_ + n) * CH + (cc - 128)];
  out[((size_t)b * 192 + cc) * N_ + n] = v;
}

extern "C" void kernel_launch(void* const* d_in, const int* in_sizes, int n_in,
                              void* d_out, int out_size, void* d_ws, size_t ws_size,
                              hipStream_t stream) {
  const float* x   = (const float*)d_in[0];
  const float* W1  = (const float*)d_in[1];
  const float* W2  = (const float*)d_in[2];
  const float* W3  = (const float*)d_in[3];
  const float* W4  = (const float*)d_in[4];
  const float* W5  = (const float*)d_in[5];
  const float* W6  = (const float*)d_in[6];
  const float* bng = (const float*)d_in[7];
  const float* bnb = (const float*)d_in[8];
  const float* bnm = (const float*)d_in[9];
  const float* bnv = (const float*)d_in[10];
  const float* g6  = (const float*)d_in[11];
  const float* b6  = (const float*)d_in[12];
  const float* m6  = (const float*)d_in[13];
  const float* v6  = (const float*)d_in[14];
  float* out = (float*)d_out;

  float* ws = (float*)d_ws;
  float* x1b  = ws;                       // 8*2048*64
  float* x2b  = x1b + 1048576;
  float* x3b  = x2b + 1048576;
  float* w6t  = x3b + 1048576;            // 192*1024
  float* w2tg = w6t + 196608;             // 4096
  float* w4tg = w2tg + 4096;              // 4096
  u32*   gkeys = (u32*)(w4tg + 4096);     // 8192
  int*   idxb  = (int*)(gkeys + 8192);    // 8*2048*20

  prep_kernel<<<768, 256, 0, stream>>>(W2, W4, W6, w2tg, w4tg, w6t, gkeys);

  knn_kernel<<<dim3(N_ / 64, B_), 256, 0, stream>>>(x, 3, 0, idxb);
  stage1_kernel<<<dim3(N_ / 4, B_), 256, 0, stream>>>(
      x, idxb, W1, w2tg,
      bng + 0, bnb + 0, bnm + 0, bnv + 0,
      bng + 64, bnb + 64, bnm + 64, bnv + 64, x1b);

  knn_kernel<<<dim3(N_ / 64, B_), 256, 0, stream>>>(x1b, 64, 6, idxb);
  stage2_kernel<<<dim3(N_ / 4, B_), 256, 0, stream>>>(
      x1b, idxb, W3, w4tg,
      bng + 128, bnb + 128, bnm + 128, bnv + 128,
      bng + 192, bnb + 192, bnm + 192, bnv + 192, x2b);

  knn_kernel<<<dim3(N_ / 64, B_), 256, 0, stream>>>(x2b, 64, 6, idxb);
  stage3_kernel<<<dim3(N_ / 4, B_), 256, 0, stream>>>(
      x2b, idxb, W5,
      bng + 256, bnb + 256, bnm + 256, bnv + 256, x3b);

  stage6_kernel<<<dim3(N_ / 16, B_), 256, 0, stream>>>(x1b, x2b, x3b, w6t, g6, b6, m6, v6, gkeys);
  feat_kernel<<<32, 256, 0, stream>>>(gkeys, out);
  xpose_kernel<<<dim3(N_ / 256, 192, B_), 256, 0, stream>>>(x1b, x2b, x3b, out + 8192);
}

// Round 2
// 948.253 us; speedup vs baseline: 2.3019x; 2.3019x over previous
//
#include <hip/hip_runtime.h>
#include <hip/hip_bf16.h>
#include <math.h>

#define B_ 8
#define N_ 2048
#define KNN 20
#define CH 64

typedef unsigned int u32;

__device__ __forceinline__ float lrelu(float z) { return z >= 0.0f ? z : 0.2f * z; }

__device__ __forceinline__ u32 enc_f32(float f) {
  u32 u = __float_as_uint(f);
  return (u & 0x80000000u) ? ~u : (u | 0x80000000u);
}
__device__ __forceinline__ float dec_f32(u32 u) {
  u32 bits = (u & 0x80000000u) ? (u ^ 0x80000000u) : ~u;
  return __uint_as_float(bits);
}

// ---------------- prep: transpose W2/W4/W6 into ws, zero gmax keys ----------------
__global__ __launch_bounds__(256) void prep_kernel(
    const float* __restrict__ W2, const float* __restrict__ W4, const float* __restrict__ W6,
    float* __restrict__ w2tg, float* __restrict__ w4tg, float* __restrict__ w6t,
    u32* __restrict__ gkeys) {
  int i = blockIdx.x * 256 + threadIdx.x;
  if (i < 192 * 1024) {          // w6t[d*1024+c] = W6[c*192+d]
    int cc = i / 192, d = i % 192;
    w6t[d * 1024 + cc] = W6[i];
  }
  if (i < 4096) {                // w2tg[cc*64+c] = W2[c*64+cc]; same for W4
    int c_ = i >> 6, cc = i & 63;
    w2tg[cc * 64 + c_] = W2[i];
    w4tg[cc * 64 + c_] = W4[i];
  }
  if (i < 8192) gkeys[i] = 0u;
}

// ---------------- KNN v2: fp32 filter + fp64 rerank ----------------
// grid (N/32, B), block 256 = 32 queries x 8 slices (slice = tid&7)
// Round 1: branchless per-lane fp32 top-3 (values only) -> threshold
//   thr = max over 8 lanes of 3rd-best. Proof of safety: if all 8 lanes' 3rd-bests
//   were inside the true top-20, the 24 distinct top-3 candidates would all be in a
//   20-element set — contradiction. So thr >= d(rank21) >= d(rank20).
// Round 2: branchless exec-masked append of passing candidate indices to LDS.
// Epilogue: per-lane exact fp64 sorted top-20 of buffered candidates; one lane per
//   query 8-way merges (d,idx)-lexicographic. Overflow (cnt>CAP) -> exact full rescan.
#define QPB 32
#define SL 8
#define CSL (N_ / SL)   // 256 candidates per slice
#define CAP 31

__global__ __launch_bounds__(256) void knn_kernel(const float* __restrict__ p, int ld, int off,
                                                  int* __restrict__ idxout) {
  __shared__ __align__(16) char arena[64640];
  float4* pts = (float4*)arena;              // [2056] skewed: pts[j + (j>>8)]  (32896 B)
  int* buf = (int*)(arena + 32896);          // [256][CAP]  (31744 B)
  double* dls = (double*)arena;              // phase 2: [256][20] doubles (40960 B)
  int* ils = (int*)(arena + 40960);          // phase 2: [256][20] ints   (20480 B)

  const int b = blockIdx.y;
  const float* pb = p + (size_t)b * N_ * ld + off;
  for (int j = threadIdx.x; j < N_; j += 256) {
    pts[j + (j >> 8)] = make_float4(pb[(size_t)j * ld + 0], pb[(size_t)j * ld + 1],
                                    pb[(size_t)j * ld + 2], 0.f);
  }
  __syncthreads();

  const int t = threadIdx.x & 7;
  const int qloc = threadIdx.x >> 3;
  const int q = blockIdx.x * QPB + qloc;
  const float4 qp = pts[q + (q >> 8)];
  const int jb = t * CSL;
  const float4* myp = pts + jb + t;          // skew: (jb+i) + ((jb+i)>>8) = jb + t + i

  // ---- round 1: branchless top-3 values ----
  float d0 = 1e30f, d1 = 1e30f, d2 = 1e30f;
#pragma unroll 4
  for (int i = 0; i < CSL; ++i) {
    float4 c = myp[i];
    float dx = qp.x - c.x, dy = qp.y - c.y, dz = qp.z - c.z;
    float d = fmaf(dz, dz, fmaf(dy, dy, dx * dx));
    float lo = fminf(d, d0); float hi = fmaxf(d, d0); d0 = lo;
    float m1 = fminf(d1, hi); float c1 = fmaxf(d1, hi); d1 = m1;
    d2 = fminf(d2, c1);
  }
  float thr = d2;
#pragma unroll
  for (int s = 1; s < 8; s <<= 1) thr = fmaxf(thr, __shfl_xor(thr, s));
  thr = thr * 1.0001f + 1e-7f;               // fp32-error margin (filter only; exactness from fp64 rerank)

  // ---- round 2: buffered filter ----
  int cnt = 0;
  int* mybuf = buf + threadIdx.x * CAP;
#pragma unroll 4
  for (int i = 0; i < CSL; ++i) {
    float4 c = myp[i];
    float dx = qp.x - c.x, dy = qp.y - c.y, dz = qp.z - c.z;
    float d = fmaf(dz, dz, fmaf(dy, dy, dx * dx));
    if (d <= thr) {
      if (cnt < CAP) mybuf[cnt] = jb + i;
      ++cnt;
    }
  }

  // ---- epilogue: exact fp64 per-lane sorted top-20 ----
  double ld_[KNN]; int li_[KNN];
#pragma unroll
  for (int u = 0; u < KNN; ++u) { ld_[u] = 1e300; li_[u] = 0x7fffffff; }

  const bool ovf = cnt > CAP;                // astronomically rare; exact fallback
  const int m = ovf ? 0 : cnt;
  for (int e = 0; e < m; ++e) {
    int j = mybuf[e];
    float4 c = pts[j + (j >> 8)];
    double dx = (double)qp.x - (double)c.x;
    double dy = (double)qp.y - (double)c.y;
    double dz = (double)qp.z - (double)c.z;
    double d = dx * dx + dy * dy + dz * dz;
    if (d < ld_[KNN - 1]) {
      ld_[KNN - 1] = d; li_[KNN - 1] = j;
#pragma unroll
      for (int u = KNN - 1; u > 0; --u) {
        if (ld_[u] < ld_[u - 1]) {
          double td = ld_[u]; ld_[u] = ld_[u - 1]; ld_[u - 1] = td;
          int ti = li_[u]; li_[u] = li_[u - 1]; li_[u - 1] = ti;
        }
      }
    }
  }
  if (ovf) {
    for (int i = 0; i < CSL; ++i) {
      int j = jb + i;
      float4 c = myp[i];
      double dx = (double)qp.x - (double)c.x;
      double dy = (double)qp.y - (double)c.y;
      double dz = (double)qp.z - (double)c.z;
      double d = dx * dx + dy * dy + dz * dz;
      if (d < ld_[KNN - 1]) {
        ld_[KNN - 1] = d; li_[KNN - 1] = j;
#pragma unroll
        for (int u = KNN - 1; u > 0; --u) {
          if (ld_[u] < ld_[u - 1]) {
            double td = ld_[u]; ld_[u] = ld_[u - 1]; ld_[u - 1] = td;
            int ti = li_[u]; li_[u] = li_[u - 1]; li_[u - 1] = ti;
          }
        }
      }
    }
  }
  __syncthreads();                           // everyone done reading pts/buf
#pragma unroll
  for (int u = 0; u < KNN; ++u) {
    dls[threadIdx.x * KNN + u] = ld_[u];
    ils[threadIdx.x * KNN + u] = li_[u];
  }
  __syncthreads();

  // ---- 8-way lexicographic merge, one lane per query ----
  if (t == 0) {
    int h0 = 0, h1 = 0, h2 = 0, h3 = 0, h4 = 0, h5 = 0, h6 = 0, h7 = 0;
    const int lb = qloc * 8;
    int* outp = idxout + ((size_t)b * N_ + q) * KNN;
    for (int r = 0; r < KNN; ++r) {
      double bd = 1e301; int bi = 0x7fffffff; int bt = 0;
#define CONSIDER(T, H)                                                     \
      { int li2 = (lb + (T)) * KNN + (H);                                  \
        double dv = dls[li2]; int iv = ils[li2];                           \
        if (dv < bd || (dv == bd && iv < bi)) { bd = dv; bi = iv; bt = (T); } }
      CONSIDER(0, h0) CONSIDER(1, h1) CONSIDER(2, h2) CONSIDER(3, h3)
      CONSIDER(4, h4) CONSIDER(5, h5) CONSIDER(6, h6) CONSIDER(7, h7)
#undef CONSIDER
      outp[r] = bi;
      h0 += (bt == 0); h1 += (bt == 1); h2 += (bt == 2); h3 += (bt == 3);
      h4 += (bt == 4); h5 += (bt == 5); h6 += (bt == 6); h7 += (bt == 7);
    }
  }
}

// ---------------- stage1: edge(3) -> 64 -> 64 -> max_k ----------------
// grid (N/4, B), block 256 = 4 points x 64 channels
__global__ __launch_bounds__(256) void stage1_kernel(
    const float* __restrict__ x, const int* __restrict__ idx,
    const float* __restrict__ W1, const float* __restrict__ w2tg,
    const float* __restrict__ g0, const float* __restrict__ b0,
    const float* __restrict__ m0, const float* __restrict__ v0,
    const float* __restrict__ g1, const float* __restrict__ b1,
    const float* __restrict__ m1, const float* __restrict__ v1,
    float* __restrict__ x1out) {
  __shared__ float w1t[6][CH];
  __shared__ float nbs[4][KNN][3];
  __shared__ float ctrs[4][3];
  __shared__ int sidx[4][KNN];
  const int b = blockIdx.y;
  const int n0 = blockIdx.x * 4;
  const int p = threadIdx.x >> 6, c = threadIdx.x & 63;

  for (int i = threadIdx.x; i < 6 * CH; i += 256) { int d = i >> 6, cc = i & 63; w1t[d][cc] = W1[cc * 6 + d]; }
  for (int i = threadIdx.x; i < 4 * KNN; i += 256)
    sidx[i / KNN][i % KNN] = idx[((size_t)b * N_ + n0 + i / KNN) * KNN + i % KNN];
  __syncthreads();
  for (int i = threadIdx.x; i < 4 * KNN * 3; i += 256) {
    int pp = i / (KNN * 3), r = i % (KNN * 3), k = r / 3, d = r % 3;
    nbs[pp][k][d] = x[((size_t)b * N_ + sidx[pp][k]) * 3 + d];
  }
  if (threadIdx.x < 12) {
    int pp = threadIdx.x / 3, d = threadIdx.x % 3;
    ctrs[pp][d] = x[((size_t)b * N_ + n0 + pp) * 3 + d];
  }
  __syncthreads();

  float sc0, sh0, sc1, sh1;
  {
    double rs = 1.0 / sqrt((double)v0[c] + 1e-5);
    sc0 = (float)((double)g0[c] * rs); sh0 = b0[c] - m0[c] * sc0;
    rs = 1.0 / sqrt((double)v1[c] + 1e-5);
    sc1 = (float)((double)g1[c] * rs); sh1 = b1[c] - m1[c] * sc1;
  }

  const float cx = ctrs[p][0], cy = ctrs[p][1], cz = ctrs[p][2];
  const float wa0 = w1t[0][c], wa1 = w1t[1][c], wa2 = w1t[2][c];
  const float wb0 = w1t[3][c], wb1 = w1t[4][c], wb2 = w1t[5][c];
  const float cbase = cx * wb0 + cy * wb1 + cz * wb2;

  float h1r[KNN];
#pragma unroll
  for (int k = 0; k < KNN; ++k) {
    float a = (nbs[p][k][0] - cx) * wa0 + (nbs[p][k][1] - cy) * wa1 + (nbs[p][k][2] - cz) * wa2 + cbase;
    h1r[k] = lrelu(a * sc0 + sh0);
  }

  float acc2[KNN];
#pragma unroll
  for (int k = 0; k < KNN; ++k) acc2[k] = 0.f;
  for (int cc = 0; cc < CH; ++cc) {
    float w = w2tg[cc * CH + c];
#pragma unroll
    for (int k = 0; k < KNN; ++k) {
      float hv = __int_as_float(__builtin_amdgcn_readlane(__float_as_int(h1r[k]), cc));
      acc2[k] += hv * w;
    }
  }
  float mx = -INFINITY;
#pragma unroll
  for (int k = 0; k < KNN; ++k) mx = fmaxf(mx, lrelu(acc2[k] * sc1 + sh1));
  x1out[((size_t)b * N_ + n0 + p) * CH + c] = mx;
}

// ---------------- stage2: edge(64) -> 64 -> 64 -> max_k ----------------
__global__ __launch_bounds__(256) void stage2_kernel(
    const float* __restrict__ xin, const int* __restrict__ idx,
    const float* __restrict__ W3, const float* __restrict__ w4tg,
    const float* __restrict__ g0, const float* __restrict__ b0,
    const float* __restrict__ m0, const float* __restrict__ v0,
    const float* __restrict__ g1, const float* __restrict__ b1,
    const float* __restrict__ m1, const float* __restrict__ v1,
    float* __restrict__ xout) {
  __shared__ float w3t[128][CH];      // 32KB
  __shared__ float nbs[4][KNN][CH];   // 20KB
  __shared__ float ctrs[4][CH];       // 1KB
  __shared__ int sidx[4][KNN];
  const int b = blockIdx.y, n0 = blockIdx.x * 4;
  const int p = threadIdx.x >> 6, c = threadIdx.x & 63;

  for (int i = threadIdx.x; i < 128 * CH; i += 256) { int cc = i >> 7, d = i & 127; w3t[d][cc] = W3[i]; }
  for (int i = threadIdx.x; i < 4 * KNN; i += 256)
    sidx[i / KNN][i % KNN] = idx[((size_t)b * N_ + n0 + i / KNN) * KNN + i % KNN];
  __syncthreads();
  for (int i = threadIdx.x; i < 4 * KNN * 16; i += 256) {
    int pp = i / (KNN * 16), r = i % (KNN * 16), k = r >> 4, d4 = (r & 15) * 4;
    const float4 v = *(const float4*)&xin[((size_t)b * N_ + sidx[pp][k]) * CH + d4];
    *(float4*)&nbs[pp][k][d4] = v;
  }
  for (int i = threadIdx.x; i < 4 * 16; i += 256) {
    int pp = i / 16, d4 = (i % 16) * 4;
    *(float4*)&ctrs[pp][d4] = *(const float4*)&xin[((size_t)b * N_ + n0 + pp) * CH + d4];
  }
  __syncthreads();

  float sc0, sh0, sc1, sh1;
  {
    double rs = 1.0 / sqrt((double)v0[c] + 1e-5);
    sc0 = (float)((double)g0[c] * rs); sh0 = b0[c] - m0[c] * sc0;
    rs = 1.0 / sqrt((double)v1[c] + 1e-5);
    sc1 = (float)((double)g1[c] * rs); sh1 = b1[c] - m1[c] * sc1;
  }

  float acc[KNN];
#pragma unroll
  for (int k = 0; k < KNN; ++k) acc[k] = 0.f;
  float base = 0.f;
  for (int d = 0; d < CH; d += 4) {
    float a0 = w3t[d + 0][c], a1 = w3t[d + 1][c], a2 = w3t[d + 2][c], a3 = w3t[d + 3][c];
    float q0 = w3t[64 + d + 0][c], q1 = w3t[64 + d + 1][c], q2 = w3t[64 + d + 2][c], q3 = w3t[64 + d + 3][c];
    const float4 ct = *(const float4*)&ctrs[p][d];
    base += ct.x * (q0 - a0) + ct.y * (q1 - a1) + ct.z * (q2 - a2) + ct.w * (q3 - a3);
#pragma unroll
    for (int k = 0; k < KNN; ++k) {
      const float4 nb = *(const float4*)&nbs[p][k][d];
      acc[k] += nb.x * a0 + nb.y * a1 + nb.z * a2 + nb.w * a3;
    }
  }
  float h1r[KNN];
#pragma unroll
  for (int k = 0; k < KNN; ++k) h1r[k] = lrelu((acc[k] + base) * sc0 + sh0);

  float acc2[KNN];
#pragma unroll
  for (int k = 0; k < KNN; ++k) acc2[k] = 0.f;
  for (int cc = 0; cc < CH; ++cc) {
    float w = w4tg[cc * CH + c];
#pragma unroll
    for (int k = 0; k < KNN; ++k) {
      float hv = __int_as_float(__builtin_amdgcn_readlane(__float_as_int(h1r[k]), cc));
      acc2[k] += hv * w;
    }
  }
  float mx = -INFINITY;
#pragma unroll
  for (int k = 0; k < KNN; ++k) mx = fmaxf(mx, lrelu(acc2[k] * sc1 + sh1));
  xout[((size_t)b * N_ + n0 + p) * CH + c] = mx;
}

// ---------------- stage3: edge(64) -> 64 -> max_k ----------------
__global__ __launch_bounds__(256) void stage3_kernel(
    const float* __restrict__ xin, const int* __restrict__ idx,
    const float* __restrict__ W5,
    const float* __restrict__ g0, const float* __restrict__ b0,
    const float* __restrict__ m0, const float* __restrict__ v0,
    float* __restrict__ xout) {
  __shared__ float w5t[128][CH];
  __shared__ float nbs[4][KNN][CH];
  __shared__ float ctrs[4][CH];
  __shared__ int sidx[4][KNN];
  const int b = blockIdx.y, n0 = blockIdx.x * 4;
  const int p = threadIdx.x >> 6, c = threadIdx.x & 63;

  for (int i = threadIdx.x; i < 128 * CH; i += 256) { int cc = i >> 7, d = i & 127; w5t[d][cc] = W5[i]; }
  for (int i = threadIdx.x; i < 4 * KNN; i += 256)
    sidx[i / KNN][i % KNN] = idx[((size_t)b * N_ + n0 + i / KNN) * KNN + i % KNN];
  __syncthreads();
  for (int i = threadIdx.x; i < 4 * KNN * 16; i += 256) {
    int pp = i / (KNN * 16), r = i % (KNN * 16), k = r >> 4, d4 = (r & 15) * 4;
    const float4 v = *(const float4*)&xin[((size_t)b * N_ + sidx[pp][k]) * CH + d4];
    *(float4*)&nbs[pp][k][d4] = v;
  }
  for (int i = threadIdx.x; i < 4 * 16; i += 256) {
    int pp = i / 16, d4 = (i % 16) * 4;
    *(float4*)&ctrs[pp][d4] = *(const float4*)&xin[((size_t)b * N_ + n0 + pp) * CH + d4];
  }
  __syncthreads();

  float sc0, sh0;
  {
    double rs = 1.0 / sqrt((double)v0[c] + 1e-5);
    sc0 = (float)((double)g0[c] * rs); sh0 = b0[c] - m0[c] * sc0;
  }

  float acc[KNN];
#pragma unroll
  for (int k = 0; k < KNN; ++k) acc[k] = 0.f;
  float base = 0.f;
  for (int d = 0; d < CH; d += 4) {
    float a0 = w5t[d + 0][c], a1 = w5t[d + 1][c], a2 = w5t[d + 2][c], a3 = w5t[d + 3][c];
    float q0 = w5t[64 + d + 0][c], q1 = w5t[64 + d + 1][c], q2 = w5t[64 + d + 2][c], q3 = w5t[64 + d + 3][c];
    const float4 ct = *(const float4*)&ctrs[p][d];
    base += ct.x * (q0 - a0) + ct.y * (q1 - a1) + ct.z * (q2 - a2) + ct.w * (q3 - a3);
#pragma unroll
    for (int k = 0; k < KNN; ++k) {
      const float4 nb = *(const float4*)&nbs[p][k][d];
      acc[k] += nb.x * a0 + nb.y * a1 + nb.z * a2 + nb.w * a3;
    }
  }
  float mx = -INFINITY;
#pragma unroll
  for (int k = 0; k < KNN; ++k) mx = fmaxf(mx, lrelu((acc[k] + base) * sc0 + sh0));
  xout[((size_t)b * N_ + n0 + p) * CH + c] = mx;
}

// ---------------- stage6: x4(192) -> 1024, BN+LReLU, block-local max + atomic ----------------
// grid (N/16, B), block 256; thread owns 4 channels, 16 points per block
__global__ __launch_bounds__(256) void stage6_kernel(
    const float* __restrict__ x1, const float* __restrict__ x2, const float* __restrict__ x3,
    const float* __restrict__ w6t,
    const float* __restrict__ g6, const float* __restrict__ b6,
    const float* __restrict__ m6, const float* __restrict__ v6,
    u32* __restrict__ gkeys) {
  __shared__ float xsT[192][16];
  const int b = blockIdx.y;
  const int n0 = blockIdx.x * 16;
  for (int i = threadIdx.x; i < 16 * 192; i += 256) {
    int d = i >> 4, pp = i & 15;
    float v;
    if (d < 64)       v = x1[((size_t)b * N_ + n0 + pp) * CH + d];
    else if (d < 128) v = x2[((size_t)b * N_ + n0 + pp) * CH + (d - 64)];
    else              v = x3[((size_t)b * N_ + n0 + pp) * CH + (d - 128)];
    xsT[d][pp] = v;
  }
  __syncthreads();

  const int c0 = threadIdx.x << 2;
  float4 acc[16];
#pragma unroll
  for (int pp = 0; pp < 16; ++pp) acc[pp] = make_float4(0.f, 0.f, 0.f, 0.f);

  for (int d = 0; d < 192; ++d) {
    const float4 w = *(const float4*)&w6t[(size_t)d * 1024 + c0];
#pragma unroll
    for (int q = 0; q < 4; ++q) {
      const float4 xq = *(const float4*)&xsT[d][q * 4];
#define ACC4(J, XV) { float4& A = acc[q * 4 + (J)]; A.x += (XV) * w.x; A.y += (XV) * w.y; A.z += (XV) * w.z; A.w += (XV) * w.w; }
      ACC4(0, xq.x) ACC4(1, xq.y) ACC4(2, xq.z) ACC4(3, xq.w)
#undef ACC4
    }
  }

  const float4 gg = *(const float4*)&g6[c0];
  const float4 bb = *(const float4*)&b6[c0];
  const float4 mm = *(const float4*)&m6[c0];
  const float4 vv = *(const float4*)&v6[c0];
  float4 s, h;
  s.x = (float)((double)gg.x / sqrt((double)vv.x + 1e-5)); h.x = bb.x - mm.x * s.x;
  s.y = (float)((double)gg.y / sqrt((double)vv.y + 1e-5)); h.y = bb.y - mm.y * s.y;
  s.z = (float)((double)gg.z / sqrt((double)vv.z + 1e-5)); h.z = bb.z - mm.z * s.z;
  s.w = (float)((double)gg.w / sqrt((double)vv.w + 1e-5)); h.w = bb.w - mm.w * s.w;

  float4 mx = make_float4(-INFINITY, -INFINITY, -INFINITY, -INFINITY);
#pragma unroll
  for (int pp = 0; pp < 16; ++pp) {
    mx.x = fmaxf(mx.x, lrelu(acc[pp].x * s.x + h.x));
    mx.y = fmaxf(mx.y, lrelu(acc[pp].y * s.y + h.y));
    mx.z = fmaxf(mx.z, lrelu(acc[pp].z * s.z + h.z));
    mx.w = fmaxf(mx.w, lrelu(acc[pp].w * s.w + h.w));
  }
  u32* gk = gkeys + (size_t)b * 1024 + c0;
  atomicMax(&gk[0], enc_f32(mx.x));
  atomicMax(&gk[1], enc_f32(mx.y));
  atomicMax(&gk[2], enc_f32(mx.z));
  atomicMax(&gk[3], enc_f32(mx.w));
}

__global__ __launch_bounds__(256) void feat_kernel(const u32* __restrict__ gkeys, float* __restrict__ out) {
  int i = blockIdx.x * 256 + threadIdx.x;
  if (i < 8192) out[i] = dec_f32(gkeys[i]);
}

// out1[b][c][n] = x4[b][n][c]; grid (N/256, 192, B)
__global__ __launch_bounds__(256) void xpose_kernel(
    const float* __restrict__ x1, const float* __restrict__ x2, const float* __restrict__ x3,
    float* __restrict__ out) {
  int n = blockIdx.x * 256 + threadIdx.x;
  int cc = blockIdx.y, b = blockIdx.z;
  float v;
  if (cc < 64)       v = x1[((size_t)b * N_ + n) * CH + cc];
  else if (cc < 128) v = x2[((size_t)b * N_ + n) * CH + (cc - 64)];
  else               v = x3[((size_t)b * N_ + n) * CH + (cc - 128)];
  out[((size_t)b * 192 + cc) * N_ + n] = v;
}

extern "C" void kernel_launch(void* const* d_in, const int* in_sizes, int n_in,
                              void* d_out, int out_size, void* d_ws, size_t ws_size,
                              hipStream_t stream) {
  const float* x   = (const float*)d_in[0];
  const float* W1  = (const float*)d_in[1];
  const float* W2  = (const float*)d_in[2];
  const float* W3  = (const float*)d_in[3];
  const float* W4  = (const float*)d_in[4];
  const float* W5  = (const float*)d_in[5];
  const float* W6  = (const float*)d_in[6];
  const float* bng = (const float*)d_in[7];
  const float* bnb = (const float*)d_in[8];
  const float* bnm = (const float*)d_in[9];
  const float* bnv = (const float*)d_in[10];
  const float* g6  = (const float*)d_in[11];
  const float* b6  = (const float*)d_in[12];
  const float* m6  = (const float*)d_in[13];
  const float* v6  = (const float*)d_in[14];
  float* out = (float*)d_out;

  float* ws = (float*)d_ws;
  float* x1b  = ws;                       // 8*2048*64
  float* x2b  = x1b + 1048576;
  float* x3b  = x2b + 1048576;
  float* w6t  = x3b + 1048576;            // 192*1024
  float* w2tg = w6t + 196608;             // 4096
  float* w4tg = w2tg + 4096;              // 4096
  u32*   gkeys = (u32*)(w4tg + 4096);     // 8192
  int*   idxb  = (int*)(gkeys + 8192);    // 8*2048*20

  prep_kernel<<<768, 256, 0, stream>>>(W2, W4, W6, w2tg, w4tg, w6t, gkeys);

  knn_kernel<<<dim3(N_ / QPB, B_), 256, 0, stream>>>(x, 3, 0, idxb);
  stage1_kernel<<<dim3(N_ / 4, B_), 256, 0, stream>>>(
      x, idxb, W1, w2tg,
      bng + 0, bnb + 0, bnm + 0, bnv + 0,
      bng + 64, bnb + 64, bnm + 64, bnv + 64, x1b);

  knn_kernel<<<dim3(N_ / QPB, B_), 256, 0, stream>>>(x1b, 64, 6, idxb);
  stage2_kernel<<<dim3(N_ / 4, B_), 256, 0, stream>>>(
      x1b, idxb, W3, w4tg,
      bng + 128, bnb + 128, bnm + 128, bnv + 128,
      bng + 192, bnb + 192, bnm + 192, bnv + 192, x2b);

  knn_kernel<<<dim3(N_ / QPB, B_), 256, 0, stream>>>(x2b, 64, 6, idxb);
  stage3_kernel<<<dim3(N_ / 4, B_), 256, 0, stream>>>(
      x2b, idxb, W5,
      bng + 256, bnb + 256, bnm + 256, bnv + 256, x3b);

  stage6_kernel<<<dim3(N_ / 16, B_), 256, 0, stream>>>(x1b, x2b, x3b, w6t, g6, b6, m6, v6, gkeys);
  feat_kernel<<<32, 256, 0, stream>>>(gkeys, out);
  xpose_kernel<<<dim3(N_ / 256, 192, B_), 256, 0, stream>>>(x1b, x2b, x3b, out + 8192);
}

// Round 3
// 791.168 us; speedup vs baseline: 2.7590x; 1.1985x over previous
//
#include <hip/hip_runtime.h>
#include <hip/hip_bf16.h>
#include <math.h>

#define B_ 8
#define N_ 2048
#define KNN 20
#define CH 64

typedef unsigned int u32;

__device__ __forceinline__ float lrelu(float z) { return z >= 0.0f ? z : 0.2f * z; }

__device__ __forceinline__ u32 enc_f32(float f) {
  u32 u = __float_as_uint(f);
  return (u & 0x80000000u) ? ~u : (u | 0x80000000u);
}
__device__ __forceinline__ float dec_f32(u32 u) {
  u32 bits = (u & 0x80000000u) ? (u ^ 0x80000000u) : ~u;
  return __uint_as_float(bits);
}

// ---------------- prep: transposed weight copies (coalesced writes), zero gmax keys ----------------
__global__ __launch_bounds__(256) void prep_kernel(
    const float* __restrict__ W2, const float* __restrict__ W3, const float* __restrict__ W4,
    const float* __restrict__ W5, const float* __restrict__ W6,
    float* __restrict__ w2tg, float* __restrict__ w3tg, float* __restrict__ w4tg,
    float* __restrict__ w5tg, float* __restrict__ w6t, u32* __restrict__ gkeys) {
  int i = blockIdx.x * 256 + threadIdx.x;
  if (i < 192 * 1024) {          // w6t[d*1024+cc] = W6[cc*192+d]  (coalesced write)
    int d = i >> 10, cc = i & 1023;
    w6t[i] = W6[cc * 192 + d];
  }
  if (i < 4096) {                // w2tg[cc*64+c] = W2[c*64+cc]; same for W4
    int c_ = i >> 6, cc = i & 63;
    w2tg[cc * 64 + c_] = W2[i];
    w4tg[cc * 64 + c_] = W4[i];
  }
  if (i < 8192) {                // w3tg[d*64+c] = W3[c*128+d]; same for W5 (coalesced write)
    int d = i >> 6, c_ = i & 63;
    w3tg[i] = W3[c_ * 128 + d];
    w5tg[i] = W5[c_ * 128 + d];
    gkeys[i] = 0u;
  }
}

// ---------------- KNN v2: fp32 filter + fp64 rerank (unchanged from R2) ----------------
#define QPB 32
#define SL 8
#define CSL (N_ / SL)   // 256 candidates per slice
#define CAP 31

__global__ __launch_bounds__(256) void knn_kernel(const float* __restrict__ p, int ld, int off,
                                                  int* __restrict__ idxout) {
  __shared__ __align__(16) char arena[64640];
  float4* pts = (float4*)arena;              // [2056] skewed: pts[j + (j>>8)]  (32896 B)
  int* buf = (int*)(arena + 32896);          // [256][CAP]  (31744 B)
  double* dls = (double*)arena;              // phase 2: [256][20] doubles (40960 B)
  int* ils = (int*)(arena + 40960);          // phase 2: [256][20] ints   (20480 B)

  const int b = blockIdx.y;
  const float* pb = p + (size_t)b * N_ * ld + off;
  for (int j = threadIdx.x; j < N_; j += 256) {
    pts[j + (j >> 8)] = make_float4(pb[(size_t)j * ld + 0], pb[(size_t)j * ld + 1],
                                    pb[(size_t)j * ld + 2], 0.f);
  }
  __syncthreads();

  const int t = threadIdx.x & 7;
  const int qloc = threadIdx.x >> 3;
  const int q = blockIdx.x * QPB + qloc;
  const float4 qp = pts[q + (q >> 8)];
  const int jb = t * CSL;
  const float4* myp = pts + jb + t;          // skew: (jb+i) + ((jb+i)>>8) = jb + t + i

  // ---- round 1: branchless top-3 values ----
  float d0 = 1e30f, d1 = 1e30f, d2 = 1e30f;
#pragma unroll 4
  for (int i = 0; i < CSL; ++i) {
    float4 c = myp[i];
    float dx = qp.x - c.x, dy = qp.y - c.y, dz = qp.z - c.z;
    float d = fmaf(dz, dz, fmaf(dy, dy, dx * dx));
    float lo = fminf(d, d0); float hi = fmaxf(d, d0); d0 = lo;
    float m1 = fminf(d1, hi); float c1 = fmaxf(d1, hi); d1 = m1;
    d2 = fminf(d2, c1);
  }
  float thr = d2;
#pragma unroll
  for (int s = 1; s < 8; s <<= 1) thr = fmaxf(thr, __shfl_xor(thr, s));
  thr = thr * 1.0001f + 1e-7f;               // fp32-error margin (filter only; exactness from fp64 rerank)

  // ---- round 2: buffered filter ----
  int cnt = 0;
  int* mybuf = buf + threadIdx.x * CAP;
#pragma unroll 4
  for (int i = 0; i < CSL; ++i) {
    float4 c = myp[i];
    float dx = qp.x - c.x, dy = qp.y - c.y, dz = qp.z - c.z;
    float d = fmaf(dz, dz, fmaf(dy, dy, dx * dx));
    if (d <= thr) {
      if (cnt < CAP) mybuf[cnt] = jb + i;
      ++cnt;
    }
  }

  // ---- epilogue: exact fp64 per-lane sorted top-20 ----
  double ld_[KNN]; int li_[KNN];
#pragma unroll
  for (int u = 0; u < KNN; ++u) { ld_[u] = 1e300; li_[u] = 0x7fffffff; }

  const bool ovf = cnt > CAP;                // astronomically rare; exact fallback
  const int m = ovf ? 0 : cnt;
  for (int e = 0; e < m; ++e) {
    int j = mybuf[e];
    float4 c = pts[j + (j >> 8)];
    double dx = (double)qp.x - (double)c.x;
    double dy = (double)qp.y - (double)c.y;
    double dz = (double)qp.z - (double)c.z;
    double d = dx * dx + dy * dy + dz * dz;
    if (d < ld_[KNN - 1]) {
      ld_[KNN - 1] = d; li_[KNN - 1] = j;
#pragma unroll
      for (int u = KNN - 1; u > 0; --u) {
        if (ld_[u] < ld_[u - 1]) {
          double td = ld_[u]; ld_[u] = ld_[u - 1]; ld_[u - 1] = td;
          int ti = li_[u]; li_[u] = li_[u - 1]; li_[u - 1] = ti;
        }
      }
    }
  }
  if (ovf) {
    for (int i = 0; i < CSL; ++i) {
      int j = jb + i;
      float4 c = myp[i];
      double dx = (double)qp.x - (double)c.x;
      double dy = (double)qp.y - (double)c.y;
      double dz = (double)qp.z - (double)c.z;
      double d = dx * dx + dy * dy + dz * dz;
      if (d < ld_[KNN - 1]) {
        ld_[KNN - 1] = d; li_[KNN - 1] = j;
#pragma unroll
        for (int u = KNN - 1; u > 0; --u) {
          if (ld_[u] < ld_[u - 1]) {
            double td = ld_[u]; ld_[u] = ld_[u - 1]; ld_[u - 1] = td;
            int ti = li_[u]; li_[u] = li_[u - 1]; li_[u - 1] = ti;
          }
        }
      }
    }
  }
  __syncthreads();                           // everyone done reading pts/buf
#pragma unroll
  for (int u = 0; u < KNN; ++u) {
    dls[threadIdx.x * KNN + u] = ld_[u];
    ils[threadIdx.x * KNN + u] = li_[u];
  }
  __syncthreads();

  // ---- 8-way lexicographic merge, one lane per query ----
  if (t == 0) {
    int h0 = 0, h1 = 0, h2 = 0, h3 = 0, h4 = 0, h5 = 0, h6 = 0, h7 = 0;
    const int lb = qloc * 8;
    int* outp = idxout + ((size_t)b * N_ + q) * KNN;
    for (int r = 0; r < KNN; ++r) {
      double bd = 1e301; int bi = 0x7fffffff; int bt = 0;
#define CONSIDER(T, H)                                                     \
      { int li2 = (lb + (T)) * KNN + (H);                                  \
        double dv = dls[li2]; int iv = ils[li2];                           \
        if (dv < bd || (dv == bd && iv < bi)) { bd = dv; bi = iv; bt = (T); } }
      CONSIDER(0, h0) CONSIDER(1, h1) CONSIDER(2, h2) CONSIDER(3, h3)
      CONSIDER(4, h4) CONSIDER(5, h5) CONSIDER(6, h6) CONSIDER(7, h7)
#undef CONSIDER
      outp[r] = bi;
      h0 += (bt == 0); h1 += (bt == 1); h2 += (bt == 2); h3 += (bt == 3);
      h4 += (bt == 4); h5 += (bt == 5); h6 += (bt == 6); h7 += (bt == 7);
    }
  }
}

// ---------------- stage1: edge(3) -> 64 -> 64 -> max_k ----------------
// grid (N/4, B), block 256 = 4 points x 64 channels
__global__ __launch_bounds__(256) void stage1_kernel(
    const float* __restrict__ x, const int* __restrict__ idx,
    const float* __restrict__ W1, const float* __restrict__ w2tg,
    const float* __restrict__ g0, const float* __restrict__ b0,
    const float* __restrict__ m0, const float* __restrict__ v0,
    const float* __restrict__ g1, const float* __restrict__ b1,
    const float* __restrict__ m1, const float* __restrict__ v1,
    float* __restrict__ x1out) {
  __shared__ float nbs[4][KNN][3];
  __shared__ float ctrs[4][3];
  __shared__ int sidx[4][KNN];
  const int b = blockIdx.y;
  const int n0 = blockIdx.x * 4;
  const int p = threadIdx.x >> 6, c = threadIdx.x & 63;

  for (int i = threadIdx.x; i < 4 * KNN; i += 256)
    sidx[i / KNN][i % KNN] = idx[((size_t)b * N_ + n0 + i / KNN) * KNN + i % KNN];
  __syncthreads();
  for (int i = threadIdx.x; i < 4 * KNN * 3; i += 256) {
    int pp = i / (KNN * 3), r = i % (KNN * 3), k = r / 3, d = r % 3;
    nbs[pp][k][d] = x[((size_t)b * N_ + sidx[pp][k]) * 3 + d];
  }
  if (threadIdx.x < 12) {
    int pp = threadIdx.x / 3, d = threadIdx.x % 3;
    ctrs[pp][d] = x[((size_t)b * N_ + n0 + pp) * 3 + d];
  }
  __syncthreads();

  float sc0, sh0, sc1, sh1;
  {
    double rs = 1.0 / sqrt((double)v0[c] + 1e-5);
    sc0 = (float)((double)g0[c] * rs); sh0 = b0[c] - m0[c] * sc0;
    rs = 1.0 / sqrt((double)v1[c] + 1e-5);
    sc1 = (float)((double)g1[c] * rs); sh1 = b1[c] - m1[c] * sc1;
  }

  const float cx = ctrs[p][0], cy = ctrs[p][1], cz = ctrs[p][2];
  const float wa0 = W1[c * 6 + 0], wa1 = W1[c * 6 + 1], wa2 = W1[c * 6 + 2];
  const float wb0 = W1[c * 6 + 3], wb1 = W1[c * 6 + 4], wb2 = W1[c * 6 + 5];
  const float cbase = cx * wb0 + cy * wb1 + cz * wb2;

  float h1r[KNN];
#pragma unroll
  for (int k = 0; k < KNN; ++k) {
    float a = (nbs[p][k][0] - cx) * wa0 + (nbs[p][k][1] - cy) * wa1 + (nbs[p][k][2] - cz) * wa2 + cbase;
    h1r[k] = lrelu(a * sc0 + sh0);
  }

  float acc2[KNN];
#pragma unroll
  for (int k = 0; k < KNN; ++k) acc2[k] = 0.f;
  for (int cc = 0; cc < CH; ++cc) {
    float w = w2tg[cc * CH + c];
#pragma unroll
    for (int k = 0; k < KNN; ++k) {
      float hv = __int_as_float(__builtin_amdgcn_readlane(__float_as_int(h1r[k]), cc));
      acc2[k] += hv * w;
    }
  }
  float mx = -INFINITY;
#pragma unroll
  for (int k = 0; k < KNN; ++k) mx = fmaxf(mx, lrelu(acc2[k] * sc1 + sh1));
  x1out[((size_t)b * N_ + n0 + p) * CH + c] = mx;
}

// ---------------- stage2: edge(64) -> 64 -> 64 -> max_k ----------------
// Weights read directly from global (L1/L2-resident, 32 KB shared by all blocks).
// LDS ~21 KB -> 4 blocks/CU.
__global__ __launch_bounds__(256) void stage2_kernel(
    const float* __restrict__ xin, const int* __restrict__ idx,
    const float* __restrict__ w3tg, const float* __restrict__ w4tg,
    const float* __restrict__ g0, const float* __restrict__ b0,
    const float* __restrict__ m0, const float* __restrict__ v0,
    const float* __restrict__ g1, const float* __restrict__ b1,
    const float* __restrict__ m1, const float* __restrict__ v1,
    float* __restrict__ xout) {
  __shared__ float nbs[4][KNN][CH];   // 20KB
  __shared__ float ctrs[4][CH];       // 1KB
  __shared__ int sidx[4][KNN];
  const int b = blockIdx.y, n0 = blockIdx.x * 4;
  const int p = threadIdx.x >> 6, c = threadIdx.x & 63;

  for (int i = threadIdx.x; i < 4 * KNN; i += 256)
    sidx[i / KNN][i % KNN] = idx[((size_t)b * N_ + n0 + i / KNN) * KNN + i % KNN];
  __syncthreads();
  for (int i = threadIdx.x; i < 4 * KNN * 16; i += 256) {
    int pp = i / (KNN * 16), r = i % (KNN * 16), k = r >> 4, d4 = (r & 15) * 4;
    const float4 v = *(const float4*)&xin[((size_t)b * N_ + sidx[pp][k]) * CH + d4];
    *(float4*)&nbs[pp][k][d4] = v;
  }
  for (int i = threadIdx.x; i < 4 * 16; i += 256) {
    int pp = i / 16, d4 = (i % 16) * 4;
    *(float4*)&ctrs[pp][d4] = *(const float4*)&xin[((size_t)b * N_ + n0 + pp) * CH + d4];
  }
  __syncthreads();

  float sc0, sh0, sc1, sh1;
  {
    double rs = 1.0 / sqrt((double)v0[c] + 1e-5);
    sc0 = (float)((double)g0[c] * rs); sh0 = b0[c] - m0[c] * sc0;
    rs = 1.0 / sqrt((double)v1[c] + 1e-5);
    sc1 = (float)((double)g1[c] * rs); sh1 = b1[c] - m1[c] * sc1;
  }

  float acc[KNN];
#pragma unroll
  for (int k = 0; k < KNN; ++k) acc[k] = 0.f;
  float base = 0.f;
#pragma unroll 4
  for (int d = 0; d < CH; d += 4) {
    float a0 = w3tg[(d + 0) * 64 + c], a1 = w3tg[(d + 1) * 64 + c];
    float a2 = w3tg[(d + 2) * 64 + c], a3 = w3tg[(d + 3) * 64 + c];
    float q0 = w3tg[(64 + d + 0) * 64 + c], q1 = w3tg[(64 + d + 1) * 64 + c];
    float q2 = w3tg[(64 + d + 2) * 64 + c], q3 = w3tg[(64 + d + 3) * 64 + c];
    const float4 ct = *(const float4*)&ctrs[p][d];
    base += ct.x * (q0 - a0) + ct.y * (q1 - a1) + ct.z * (q2 - a2) + ct.w * (q3 - a3);
#pragma unroll
    for (int k = 0; k < KNN; ++k) {
      const float4 nb = *(const float4*)&nbs[p][k][d];
      acc[k] += nb.x * a0 + nb.y * a1 + nb.z * a2 + nb.w * a3;
    }
  }
  float h1r[KNN];
#pragma unroll
  for (int k = 0; k < KNN; ++k) h1r[k] = lrelu((acc[k] + base) * sc0 + sh0);

  float acc2[KNN];
#pragma unroll
  for (int k = 0; k < KNN; ++k) acc2[k] = 0.f;
  for (int cc = 0; cc < CH; ++cc) {
    float w = w4tg[cc * CH + c];
#pragma unroll
    for (int k = 0; k < KNN; ++k) {
      float hv = __int_as_float(__builtin_amdgcn_readlane(__float_as_int(h1r[k]), cc));
      acc2[k] += hv * w;
    }
  }
  float mx = -INFINITY;
#pragma unroll
  for (int k = 0; k < KNN; ++k) mx = fmaxf(mx, lrelu(acc2[k] * sc1 + sh1));
  xout[((size_t)b * N_ + n0 + p) * CH + c] = mx;
}

// ---------------- stage3: edge(64) -> 64 -> max_k ----------------
__global__ __launch_bounds__(256) void stage3_kernel(
    const float* __restrict__ xin, const int* __restrict__ idx,
    const float* __restrict__ w5tg,
    const float* __restrict__ g0, const float* __restrict__ b0,
    const float* __restrict__ m0, const float* __restrict__ v0,
    float* __restrict__ xout) {
  __shared__ float nbs[4][KNN][CH];
  __shared__ float ctrs[4][CH];
  __shared__ int sidx[4][KNN];
  const int b = blockIdx.y, n0 = blockIdx.x * 4;
  const int p = threadIdx.x >> 6, c = threadIdx.x & 63;

  for (int i = threadIdx.x; i < 4 * KNN; i += 256)
    sidx[i / KNN][i % KNN] = idx[((size_t)b * N_ + n0 + i / KNN) * KNN + i % KNN];
  __syncthreads();
  for (int i = threadIdx.x; i < 4 * KNN * 16; i += 256) {
    int pp = i / (KNN * 16), r = i % (KNN * 16), k = r >> 4, d4 = (r & 15) * 4;
    const float4 v = *(const float4*)&xin[((size_t)b * N_ + sidx[pp][k]) * CH + d4];
    *(float4*)&nbs[pp][k][d4] = v;
  }
  for (int i = threadIdx.x; i < 4 * 16; i += 256) {
    int pp = i / 16, d4 = (i % 16) * 4;
    *(float4*)&ctrs[pp][d4] = *(const float4*)&xin[((size_t)b * N_ + n0 + pp) * CH + d4];
  }
  __syncthreads();

  float sc0, sh0;
  {
    double rs = 1.0 / sqrt((double)v0[c] + 1e-5);
    sc0 = (float)((double)g0[c] * rs); sh0 = b0[c] - m0[c] * sc0;
  }

  float acc[KNN];
#pragma unroll
  for (int k = 0; k < KNN; ++k) acc[k] = 0.f;
  float base = 0.f;
#pragma unroll 4
  for (int d = 0; d < CH; d += 4) {
    float a0 = w5tg[(d + 0) * 64 + c], a1 = w5tg[(d + 1) * 64 + c];
    float a2 = w5tg[(d + 2) * 64 + c], a3 = w5tg[(d + 3) * 64 + c];
    float q0 = w5tg[(64 + d + 0) * 64 + c], q1 = w5tg[(64 + d + 1) * 64 + c];
    float q2 = w5tg[(64 + d + 2) * 64 + c], q3 = w5tg[(64 + d + 3) * 64 + c];
    const float4 ct = *(const float4*)&ctrs[p][d];
    base += ct.x * (q0 - a0) + ct.y * (q1 - a1) + ct.z * (q2 - a2) + ct.w * (q3 - a3);
#pragma unroll
    for (int k = 0; k < KNN; ++k) {
      const float4 nb = *(const float4*)&nbs[p][k][d];
      acc[k] += nb.x * a0 + nb.y * a1 + nb.z * a2 + nb.w * a3;
    }
  }
  float mx = -INFINITY;
#pragma unroll
  for (int k = 0; k < KNN; ++k) mx = fmaxf(mx, lrelu((acc[k] + base) * sc0 + sh0));
  xout[((size_t)b * N_ + n0 + p) * CH + c] = mx;
}

// ---------------- stage6: x4(192) -> 1024, BN+LReLU, block-local max + atomic ----------------
// grid (N/16, B), block 256; thread owns 4 channels, 16 points per block
__global__ __launch_bounds__(256) void stage6_kernel(
    const float* __restrict__ x1, const float* __restrict__ x2, const float* __restrict__ x3,
    const float* __restrict__ w6t,
    const float* __restrict__ g6, const float* __restrict__ b6,
    const float* __restrict__ m6, const float* __restrict__ v6,
    u32* __restrict__ gkeys) {
  __shared__ float xsT[192][16];
  const int b = blockIdx.y;
  const int n0 = blockIdx.x * 16;
  for (int i = threadIdx.x; i < 16 * 192; i += 256) {
    int d = i >> 4, pp = i & 15;
    float v;
    if (d < 64)       v = x1[((size_t)b * N_ + n0 + pp) * CH + d];
    else if (d < 128) v = x2[((size_t)b * N_ + n0 + pp) * CH + (d - 64)];
    else              v = x3[((size_t)b * N_ + n0 + pp) * CH + (d - 128)];
    xsT[d][pp] = v;
  }
  __syncthreads();

  const int c0 = threadIdx.x << 2;
  float4 acc[16];
#pragma unroll
  for (int pp = 0; pp < 16; ++pp) acc[pp] = make_float4(0.f, 0.f, 0.f, 0.f);

  for (int d = 0; d < 192; ++d) {
    const float4 w = *(const float4*)&w6t[(size_t)d * 1024 + c0];
#pragma unroll
    for (int q = 0; q < 4; ++q) {
      const float4 xq = *(const float4*)&xsT[d][q * 4];
#define ACC4(J, XV) { float4& A = acc[q * 4 + (J)]; A.x += (XV) * w.x; A.y += (XV) * w.y; A.z += (XV) * w.z; A.w += (XV) * w.w; }
      ACC4(0, xq.x) ACC4(1, xq.y) ACC4(2, xq.z) ACC4(3, xq.w)
#undef ACC4
    }
  }

  const float4 gg = *(const float4*)&g6[c0];
  const float4 bb = *(const float4*)&b6[c0];
  const float4 mm = *(const float4*)&m6[c0];
  const float4 vv = *(const float4*)&v6[c0];
  float4 s, h;
  s.x = (float)((double)gg.x / sqrt((double)vv.x + 1e-5)); h.x = bb.x - mm.x * s.x;
  s.y = (float)((double)gg.y / sqrt((double)vv.y + 1e-5)); h.y = bb.y - mm.y * s.y;
  s.z = (float)((double)gg.z / sqrt((double)vv.z + 1e-5)); h.z = bb.z - mm.z * s.z;
  s.w = (float)((double)gg.w / sqrt((double)vv.w + 1e-5)); h.w = bb.w - mm.w * s.w;

  float4 mx = make_float4(-INFINITY, -INFINITY, -INFINITY, -INFINITY);
#pragma unroll
  for (int pp = 0; pp < 16; ++pp) {
    mx.x = fmaxf(mx.x, lrelu(acc[pp].x * s.x + h.x));
    mx.y = fmaxf(mx.y, lrelu(acc[pp].y * s.y + h.y));
    mx.z = fmaxf(mx.z, lrelu(acc[pp].z * s.z + h.z));
    mx.w = fmaxf(mx.w, lrelu(acc[pp].w * s.w + h.w));
  }
  u32* gk = gkeys + (size_t)b * 1024 + c0;
  atomicMax(&gk[0], enc_f32(mx.x));
  atomicMax(&gk[1], enc_f32(mx.y));
  atomicMax(&gk[2], enc_f32(mx.z));
  atomicMax(&gk[3], enc_f32(mx.w));
}

__global__ __launch_bounds__(256) void feat_kernel(const u32* __restrict__ gkeys, float* __restrict__ out) {
  int i = blockIdx.x * 256 + threadIdx.x;
  if (i < 8192) out[i] = dec_f32(gkeys[i]);
}

// out1[b][c][n] = x4[b][n][c]; LDS-tiled transpose. grid (N/64, B), block 256.
__global__ __launch_bounds__(256) void xpose_kernel(
    const float* __restrict__ x1, const float* __restrict__ x2, const float* __restrict__ x3,
    float* __restrict__ out) {
  __shared__ float tile[64][65];
  const int b = blockIdx.y;
  const int n0 = blockIdx.x * 64;
  const float* srcs[3] = {x1, x2, x3};
#pragma unroll
  for (int s = 0; s < 3; ++s) {
    const float* src = srcs[s];
    {
      const int row = threadIdx.x >> 2, cb = (threadIdx.x & 3) * 16;
      const float4* rp = (const float4*)&src[((size_t)b * N_ + n0 + row) * CH + cb];
      float4 v0 = rp[0], v1 = rp[1], v2 = rp[2], v3 = rp[3];
      float* tp = &tile[row][cb];
      tp[0] = v0.x; tp[1] = v0.y; tp[2] = v0.z; tp[3] = v0.w;
      tp[4] = v1.x; tp[5] = v1.y; tp[6] = v1.z; tp[7] = v1.w;
      tp[8] = v2.x; tp[9] = v2.y; tp[10] = v2.z; tp[11] = v2.w;
      tp[12] = v3.x; tp[13] = v3.y; tp[14] = v3.z; tp[15] = v3.w;
    }
    __syncthreads();
    {
      const int n = threadIdx.x & 63;
      const int cg = (threadIdx.x >> 6) * 16;
      for (int c = cg; c < cg + 16; ++c)
        out[((size_t)b * 192 + s * 64 + c) * N_ + n0 + n] = tile[n][c];
    }
    __syncthreads();
  }
}

extern "C" void kernel_launch(void* const* d_in, const int* in_sizes, int n_in,
                              void* d_out, int out_size, void* d_ws, size_t ws_size,
                              hipStream_t stream) {
  const float* x   = (const float*)d_in[0];
  const float* W1  = (const float*)d_in[1];
  const float* W2  = (const float*)d_in[2];
  const float* W3  = (const float*)d_in[3];
  const float* W4  = (const float*)d_in[4];
  const float* W5  = (const float*)d_in[5];
  const float* W6  = (const float*)d_in[6];
  const float* bng = (const float*)d_in[7];
  const float* bnb = (const float*)d_in[8];
  const float* bnm = (const float*)d_in[9];
  const float* bnv = (const float*)d_in[10];
  const float* g6  = (const float*)d_in[11];
  const float* b6  = (const float*)d_in[12];
  const float* m6  = (const float*)d_in[13];
  const float* v6  = (const float*)d_in[14];
  float* out = (float*)d_out;

  float* ws = (float*)d_ws;
  float* x1b  = ws;                       // 8*2048*64
  float* x2b  = x1b + 1048576;
  float* x3b  = x2b + 1048576;
  float* w6t  = x3b + 1048576;            // 192*1024
  float* w2tg = w6t + 196608;             // 4096
  float* w4tg = w2tg + 4096;              // 4096
  float* w3tg = w4tg + 4096;              // 8192
  float* w5tg = w3tg + 8192;              // 8192
  u32*   gkeys = (u32*)(w5tg + 8192);     // 8192
  int*   idxb  = (int*)(gkeys + 8192);    // 8*2048*20

  prep_kernel<<<768, 256, 0, stream>>>(W2, W3, W4, W5, W6, w2tg, w3tg, w4tg, w5tg, w6t, gkeys);

  knn_kernel<<<dim3(N_ / QPB, B_), 256, 0, stream>>>(x, 3, 0, idxb);
  stage1_kernel<<<dim3(N_ / 4, B_), 256, 0, stream>>>(
      x, idxb, W1, w2tg,
      bng + 0, bnb + 0, bnm + 0, bnv + 0,
      bng + 64, bnb + 64, bnm + 64, bnv + 64, x1b);

  knn_kernel<<<dim3(N_ / QPB, B_), 256, 0, stream>>>(x1b, 64, 6, idxb);
  stage2_kernel<<<dim3(N_ / 4, B_), 256, 0, stream>>>(
      x1b, idxb, w3tg, w4tg,
      bng + 128, bnb + 128, bnm + 128, bnv + 128,
      bng + 192, bnb + 192, bnm + 192, bnv + 192, x2b);

  knn_kernel<<<dim3(N_ / QPB, B_), 256, 0, stream>>>(x2b, 64, 6, idxb);
  stage3_kernel<<<dim3(N_ / 4, B_), 256, 0, stream>>>(
      x2b, idxb, w5tg,
      bng + 256, bnb + 256, bnm + 256, bnv + 256, x3b);

  stage6_kernel<<<dim3(N_ / 16, B_), 256, 0, stream>>>(x1b, x2b, x3b, w6t, g6, b6, m6, v6, gkeys);
  feat_kernel<<<32, 256, 0, stream>>>(gkeys, out);
  xpose_kernel<<<dim3(N_ / 64, B_), 256, 0, stream>>>(x1b, x2b, x3b, out + 8192);
}